// Round 5
// baseline (815.945 us; speedup 1.0000x reference)
//
#include <hip/hip_runtime.h>

#define N_NODES 50000
#define E_EDGES 800000
#define IN_F 256
#define H_F 128
#define C_OUT 10
#define NCHUNK 8
#define CHW 16            // floats per feature chunk (64 B = 1 cache line)
#define BATCH 64          // nodes per queue pop
#define NUNITS ((N_NODES + BATCH - 1) / BATCH)   // 782
#define NB_SCAN ((N_NODES + 255) / 256)   // 196, must be <= 256
static_assert(NB_SCAN <= 256, "scan2 assumes <=256 partials");

// ---------------- CSR build: count, scan, bucket ----------------

__global__ __launch_bounds__(256) void k_zero_cnt(int* __restrict__ cnt) {
    int i = blockIdx.x * 256 + threadIdx.x;
    if (i < N_NODES) cnt[i] = 0;
}

__global__ __launch_bounds__(256) void k_count(const int* __restrict__ dst,
                                               int* __restrict__ cnt) {
    int e = blockIdx.x * 256 + threadIdx.x;
    if (e < E_EDGES) atomicAdd(&cnt[dst[e]], 1);
}

__global__ __launch_bounds__(256) void k_scan1(const int* __restrict__ cnt,
                                               int* __restrict__ row_off,
                                               int* __restrict__ part) {
    __shared__ int sm[256];
    int tid = threadIdx.x;
    int i = blockIdx.x * 256 + tid;
    int v = (i < N_NODES) ? cnt[i] : 0;
    sm[tid] = v;
    __syncthreads();
#pragma unroll
    for (int off = 1; off < 256; off <<= 1) {
        int t = (tid >= off) ? sm[tid - off] : 0;
        __syncthreads();
        sm[tid] += t;
        __syncthreads();
    }
    if (i < N_NODES) row_off[i] = sm[tid] - v;   // exclusive
    if (tid == 255) part[blockIdx.x] = sm[255];  // block total
}

// scan of block totals + zero the agg work queues (16 ints)
__global__ __launch_bounds__(256) void k_scan2(int* __restrict__ part,
                                               int* __restrict__ queues) {
    __shared__ int sm[256];
    int tid = threadIdx.x;
    if (tid < 2 * NCHUNK) queues[tid] = 0;
    int v = (tid < NB_SCAN) ? part[tid] : 0;
    sm[tid] = v;
    __syncthreads();
#pragma unroll
    for (int off = 1; off < 256; off <<= 1) {
        int t = (tid >= off) ? sm[tid - off] : 0;
        __syncthreads();
        sm[tid] += t;
        __syncthreads();
    }
    if (tid < NB_SCAN) part[tid] = sm[tid] - v;  // exclusive
}

__global__ __launch_bounds__(256) void k_scan3(const int* __restrict__ cnt,
                                               const int* __restrict__ part,
                                               int* __restrict__ row_off,
                                               int* __restrict__ cursor,
                                               float* __restrict__ dinv) {
    int i = blockIdx.x * 256 + threadIdx.x;
    if (i >= N_NODES) return;
    int ro = row_off[i] + part[blockIdx.x];
    row_off[i] = ro;
    cursor[i] = ro;
    dinv[i] = rsqrtf((float)(cnt[i] + 1));
}

// permute edges into CSR slots; pack (src, weight) into one int2
__global__ __launch_bounds__(256) void k_bucket(const int* __restrict__ src,
                                                const int* __restrict__ dst,
                                                const float* __restrict__ dinv,
                                                int* __restrict__ cursor,
                                                int2* __restrict__ csr) {
    int e = blockIdx.x * 256 + threadIdx.x;
    if (e >= E_EDGES) return;
    int s = src[e], d = dst[e];
    int pos = atomicAdd(&cursor[d], 1);
    csr[pos] = make_int2(s, __float_as_int(dinv[s] * dinv[d]));
}

// ---------------- XCD-pinned chunked aggregation ----------------
// Each wave reads its physical XCD id, drains the per-XCD queue for
// feature-chunk == xcd (3.2 MB hW slice -> L2-resident gathers), then
// work-steals other chunks (correct under ANY xcd mapping).
// Wave layout: 64 lanes = 16 edge-slots x float4 (one 64B line per edge).

__device__ __forceinline__ int xcd_id() {
    int x;
    asm volatile("s_getreg_b32 %0, hwreg(HW_REG_XCC_ID)" : "=s"(x));
    return x & (NCHUNK - 1);
}

__global__ __launch_bounds__(256) void k_agg(const float* __restrict__ hW,
                                             const int* __restrict__ row_off,
                                             const int* __restrict__ cnt,
                                             const int2* __restrict__ csr,
                                             const float* __restrict__ dinv,
                                             const float* __restrict__ bias,
                                             int* __restrict__ queue,
                                             float* __restrict__ h) {
    const int lane = threadIdx.x & 63;
    const int fq   = lane & 3;        // float4 quarter within the chunk
    const int slot = lane >> 2;       // edge slot 0..15
    const int xcd  = xcd_id();

    for (int k = 0; k < NCHUNK; ++k) {
        const int ch = (xcd + k) & (NCHUNK - 1);
        const int coff = ch * CHW + fq * 4;
        int* q = queue + ch;
        while (true) {
            int u = 0;
            if (lane == 0) {
                int snap = __hip_atomic_load(q, __ATOMIC_RELAXED,
                                             __HIP_MEMORY_SCOPE_AGENT);
                u = (snap < NUNITS) ? atomicAdd(q, 1) : NUNITS;
            }
            u = __shfl(u, 0, 64);
            if (u >= NUNITS) break;
            const int n1 = min(u * BATCH + BATCH, N_NODES);
#pragma unroll 2
            for (int node = u * BATCH; node < n1; ++node) {
                const int beg = row_off[node];
                const int c = cnt[node];
                float4 acc = make_float4(0.f, 0.f, 0.f, 0.f);
                for (int r0 = 0; r0 < c; r0 += 16) {
                    if (slot < c - r0) {
                        int2 e = csr[beg + r0 + slot];
                        float w = __int_as_float(e.y);
                        float4 v = *(const float4*)(hW + (size_t)e.x * H_F + coff);
                        acc.x = fmaf(w, v.x, acc.x);
                        acc.y = fmaf(w, v.y, acc.y);
                        acc.z = fmaf(w, v.z, acc.z);
                        acc.w = fmaf(w, v.w, acc.w);
                    }
                }
#pragma unroll
                for (int m = 4; m <= 32; m <<= 1) {
                    acc.x += __shfl_xor(acc.x, m, 64);
                    acc.y += __shfl_xor(acc.y, m, 64);
                    acc.z += __shfl_xor(acc.z, m, 64);
                    acc.w += __shfl_xor(acc.w, m, 64);
                }
                if (slot == 0) {   // lanes 0..3 cover the 16-float chunk
                    float iv = dinv[node];
                    float s2 = iv * iv;
                    float rd = 1.0f / (float)(c + 1);
                    float4 sv = *(const float4*)(hW + (size_t)node * H_F + coff);
                    float4 bv = *(const float4*)(bias + coff);
                    float4 o;
                    o.x = fmaxf(fmaf(fmaf(sv.x, s2, acc.x), rd, bv.x), 0.f);
                    o.y = fmaxf(fmaf(fmaf(sv.y, s2, acc.y), rd, bv.y), 0.f);
                    o.z = fmaxf(fmaf(fmaf(sv.z, s2, acc.z), rd, bv.z), 0.f);
                    o.w = fmaxf(fmaf(fmaf(sv.w, s2, acc.w), rd, bv.w), 0.f);
                    *(float4*)(h + (size_t)node * H_F + coff) = o;
                }
            }
        }
    }
}

// ---------------- fp32 GEMM: C[M x 128] = A[M x K] @ B[K x 128] ----------------
// 64x128 tile per 256-thread block, BK=32, 4x8 per thread.

template <int K>
__global__ __launch_bounds__(256, 4) void k_gemm(const float* __restrict__ A,
                                                 const float* __restrict__ B,
                                                 float* __restrict__ C) {
    __shared__ float As[32][68];
    __shared__ float Bs[32][132];
    const int tid = threadIdx.x;
    const int brow = blockIdx.x * 64;
    const int tr4 = (tid >> 4) * 4;
    const int tc4 = (tid & 15) * 4;
    const int ar  = tid >> 2;
    const int akk = (tid & 3) * 4;
    const int bqr = tid >> 5;
    const int bqc = (tid & 31) * 4;

    float acc[4][8] = {};
    const int arow_g = brow + ar;
    const bool arow_ok = arow_g < N_NODES;
    const float* Arow = A + (size_t)arow_g * K;

    for (int kt = 0; kt < K; kt += 32) {
        float4 va0 = make_float4(0.f, 0.f, 0.f, 0.f), va1 = va0;
        if (arow_ok) {
            va0 = *(const float4*)(Arow + kt + akk);
            va1 = *(const float4*)(Arow + kt + akk + 16);
        }
        As[akk + 0][ar] = va0.x;  As[akk + 1][ar] = va0.y;
        As[akk + 2][ar] = va0.z;  As[akk + 3][ar] = va0.w;
        As[akk + 16][ar] = va1.x; As[akk + 17][ar] = va1.y;
        As[akk + 18][ar] = va1.z; As[akk + 19][ar] = va1.w;
#pragma unroll
        for (int q = 0; q < 4; ++q) {
            int r = q * 8 + bqr;
            *(float4*)&Bs[r][bqc] = *(const float4*)(B + (size_t)(kt + r) * H_F + bqc);
        }
        __syncthreads();
#pragma unroll
        for (int k = 0; k < 32; ++k) {
            float4 a4 = *(const float4*)&As[k][tr4];
            float4 b0 = *(const float4*)&Bs[k][tc4];
            float4 b1 = *(const float4*)&Bs[k][tc4 + 64];
            float av[4] = {a4.x, a4.y, a4.z, a4.w};
            float bv[8] = {b0.x, b0.y, b0.z, b0.w, b1.x, b1.y, b1.z, b1.w};
#pragma unroll
            for (int i = 0; i < 4; ++i)
#pragma unroll
                for (int jj = 0; jj < 8; ++jj)
                    acc[i][jj] = fmaf(av[i], bv[jj], acc[i][jj]);
        }
        __syncthreads();
    }
#pragma unroll
    for (int i = 0; i < 4; ++i) {
        int gr = brow + tr4 + i;
        if (gr < N_NODES) {
            float4 c0 = {acc[i][0], acc[i][1], acc[i][2], acc[i][3]};
            float4 c1 = {acc[i][4], acc[i][5], acc[i][6], acc[i][7]};
            *(float4*)(C + (size_t)gr * H_F + tc4) = c0;
            *(float4*)(C + (size_t)gr * H_F + tc4 + 64) = c1;
        }
    }
}

// ---------------- classifier: out[N x 10] = H @ Wc + bc ----------------
// one wave per node; lane owns features 2l, 2l+1; shfl-reduce.

__global__ __launch_bounds__(256) void k_out(const float* __restrict__ Hf,
                                             const float* __restrict__ Wc,
                                             const float* __restrict__ bc,
                                             float* __restrict__ out) {
    int node = blockIdx.x * 4 + (threadIdx.x >> 6);
    int lane = threadIdx.x & 63;
    if (node >= N_NODES) return;
    float2 hv = ((const float2*)Hf)[(size_t)node * 64 + lane];
    float po[C_OUT];
#pragma unroll
    for (int cc = 0; cc < C_OUT; ++cc)
        po[cc] = fmaf(hv.x, Wc[(2 * lane) * C_OUT + cc],
                      hv.y * Wc[(2 * lane + 1) * C_OUT + cc]);
#pragma unroll
    for (int off = 32; off; off >>= 1)
#pragma unroll
        for (int cc = 0; cc < C_OUT; ++cc)
            po[cc] += __shfl_xor(po[cc], off, 64);
    if (lane == 0) {
#pragma unroll
        for (int cc = 0; cc < C_OUT; ++cc)
            out[(size_t)node * C_OUT + cc] = po[cc] + bc[cc];
    }
}

// ---------------- launch ----------------

extern "C" void kernel_launch(void* const* d_in, const int* in_sizes, int n_in,
                              void* d_out, int out_size, void* d_ws, size_t ws_size,
                              hipStream_t stream) {
    const float* x  = (const float*)d_in[0];
    const int*   ei = (const int*)d_in[1];
    const float* W1 = (const float*)d_in[2];
    const float* b1 = (const float*)d_in[3];
    const float* W2 = (const float*)d_in[4];
    const float* b2 = (const float*)d_in[5];
    const float* Wc = (const float*)d_in[6];
    const float* bc = (const float*)d_in[7];
    const int* esrc = ei;
    const int* edst = ei + E_EDGES;

    char* ws = (char*)d_ws;
    int*   cnt     = (int*)ws;                    ws += sizeof(int) * N_NODES;
    int*   row_off = (int*)ws;                    ws += sizeof(int) * N_NODES;
    int*   cursor  = (int*)ws;                    ws += sizeof(int) * N_NODES;
    float* dinv    = (float*)ws;                  ws += sizeof(float) * N_NODES;
    int*   part    = (int*)ws;                    ws += sizeof(int) * 256;
    int*   queues  = (int*)ws;                    ws += sizeof(int) * 2 * NCHUNK;
    ws = (char*)(((size_t)ws + 15) & ~(size_t)15);
    int2*  csr     = (int2*)ws;                   ws += sizeof(int2) * E_EDGES;
    float* bufA    = (float*)ws;                  ws += sizeof(float) * (size_t)N_NODES * H_F;
    float* bufC    = (float*)ws;
    float* out = (float*)d_out;

    const int gN = (N_NODES + 255) / 256;
    const int gE = (E_EDGES + 255) / 256;
    const int gAgg = 2048;                 // ~8 blocks/CU, queue-drained
    const int gGemm = (N_NODES + 63) / 64;
    const int gOut = (N_NODES + 3) / 4;

    // CSR build (graph fixed per call; rebuilt every call for determinism)
    k_zero_cnt<<<gN, 256, 0, stream>>>(cnt);
    k_count<<<gE, 256, 0, stream>>>(edst, cnt);
    k_scan1<<<NB_SCAN, 256, 0, stream>>>(cnt, row_off, part);
    k_scan2<<<1, 256, 0, stream>>>(part, queues);
    k_scan3<<<NB_SCAN, 256, 0, stream>>>(cnt, part, row_off, cursor, dinv);
    k_bucket<<<gE, 256, 0, stream>>>(esrc, edst, dinv, cursor, csr);

    // layer 1
    k_gemm<IN_F><<<gGemm, 256, 0, stream>>>(x, W1, bufA);
    k_agg<<<gAgg, 256, 0, stream>>>(bufA, row_off, cnt, csr, dinv, b1,
                                    queues, bufC);

    // layer 2
    k_gemm<H_F><<<gGemm, 256, 0, stream>>>(bufC, W2, bufA);
    k_agg<<<gAgg, 256, 0, stream>>>(bufA, row_off, cnt, csr, dinv, b2,
                                    queues + NCHUNK, bufC);

    // classifier
    k_out<<<gOut, 256, 0, stream>>>(bufC, Wc, bc, out);
}

// Round 6
// 303.299 us; speedup vs baseline: 2.6902x; 2.6902x over previous
//
#include <hip/hip_runtime.h>

#define N_NODES 50000
#define E_EDGES 800000
#define IN_F 256
#define H_F 128
#define C_OUT 10
#define NB_SCAN ((N_NODES + 255) / 256)   // 196, must be <= 256
static_assert(NB_SCAN <= 256, "scan2 assumes <=256 partials");

// ---------------- CSR build: count, scan, bucket ----------------

__global__ __launch_bounds__(256) void k_zero_cnt(int* __restrict__ cnt) {
    int i = blockIdx.x * 256 + threadIdx.x;
    if (i < N_NODES) cnt[i] = 0;
}

__global__ __launch_bounds__(256) void k_count(const int* __restrict__ dst,
                                               int* __restrict__ cnt) {
    int e = blockIdx.x * 256 + threadIdx.x;
    if (e < E_EDGES) atomicAdd(&cnt[dst[e]], 1);
}

__global__ __launch_bounds__(256) void k_scan1(const int* __restrict__ cnt,
                                               int* __restrict__ row_off,
                                               int* __restrict__ part) {
    __shared__ int sm[256];
    int tid = threadIdx.x;
    int i = blockIdx.x * 256 + tid;
    int v = (i < N_NODES) ? cnt[i] : 0;
    sm[tid] = v;
    __syncthreads();
#pragma unroll
    for (int off = 1; off < 256; off <<= 1) {
        int t = (tid >= off) ? sm[tid - off] : 0;
        __syncthreads();
        sm[tid] += t;
        __syncthreads();
    }
    if (i < N_NODES) row_off[i] = sm[tid] - v;   // exclusive
    if (tid == 255) part[blockIdx.x] = sm[255];  // block total
}

__global__ __launch_bounds__(256) void k_scan2(int* __restrict__ part) {
    __shared__ int sm[256];
    int tid = threadIdx.x;
    int v = (tid < NB_SCAN) ? part[tid] : 0;
    sm[tid] = v;
    __syncthreads();
#pragma unroll
    for (int off = 1; off < 256; off <<= 1) {
        int t = (tid >= off) ? sm[tid - off] : 0;
        __syncthreads();
        sm[tid] += t;
        __syncthreads();
    }
    if (tid < NB_SCAN) part[tid] = sm[tid] - v;  // exclusive
}

__global__ __launch_bounds__(256) void k_scan3(const int* __restrict__ cnt,
                                               const int* __restrict__ part,
                                               int* __restrict__ row_off,
                                               int* __restrict__ cursor,
                                               float* __restrict__ dinv) {
    int i = blockIdx.x * 256 + threadIdx.x;
    if (i >= N_NODES) return;
    int ro = row_off[i] + part[blockIdx.x];
    row_off[i] = ro;
    cursor[i] = ro;
    dinv[i] = rsqrtf((float)(cnt[i] + 1));
}

// permute edges into CSR slots (src index only; weights folded into hW')
__global__ __launch_bounds__(256) void k_bucket(const int* __restrict__ src,
                                                const int* __restrict__ dst,
                                                int* __restrict__ cursor,
                                                int* __restrict__ csr_src) {
    int e = blockIdx.x * 256 + threadIdx.x;
    if (e >= E_EDGES) return;
    int s = src[e], d = dst[e];
    int pos = atomicAdd(&cursor[d], 1);
    csr_src[pos] = s;
}

// ---------------- fused aggregate + mean + bias + relu (+ classifier) ----------------
// hWs rows are pre-scaled by dinv (GEMM epilogue). Per node:
//   o = relu( dinv[d] * (sum_edges hWs[src] + hWs[d]) / (cnt+1) + bias )
// Wave layout: one node/wave; lane = (half, slice): 32 lanes x float4 cover the
// 128-float row; the two halves process even/odd edges -> 2 rows (1 KB) per
// gather instruction, unroll 2 -> 4 rows in flight.

template <bool FUSE_OUT>
__global__ __launch_bounds__(256) void k_agg(const float* __restrict__ hWs,
                                             const int* __restrict__ row_off,
                                             const int* __restrict__ cnt,
                                             const int* __restrict__ csr_src,
                                             const float* __restrict__ dinv,
                                             const float* __restrict__ bias,
                                             const float* __restrict__ Wc,
                                             const float* __restrict__ bc,
                                             float* __restrict__ outp) {
    const int node = blockIdx.x * 4 + (threadIdx.x >> 6);
    if (node >= N_NODES) return;
    const int lane = threadIdx.x & 63;
    const int half = lane >> 5;        // even/odd edge stream
    const int sl   = lane & 31;        // float4 slice of the row
    const int co   = sl * 4;

    const int beg = row_off[node];
    const int c   = cnt[node];
    const int ch  = (c - half + 1) >> 1;     // edges in this half's stream

    float4 acc = make_float4(0.f, 0.f, 0.f, 0.f);
    const int* ep = csr_src + beg + half;
    int k = 0;
    for (; k + 2 <= ch; k += 2) {
        int s0 = ep[0];
        int s1 = ep[2];
        ep += 4;
        float4 v0 = *(const float4*)(hWs + (size_t)s0 * H_F + co);
        float4 v1 = *(const float4*)(hWs + (size_t)s1 * H_F + co);
        acc.x += v0.x + v1.x; acc.y += v0.y + v1.y;
        acc.z += v0.z + v1.z; acc.w += v0.w + v1.w;
    }
    if (k < ch) {
        int s0 = ep[0];
        float4 v0 = *(const float4*)(hWs + (size_t)s0 * H_F + co);
        acc.x += v0.x; acc.y += v0.y; acc.z += v0.z; acc.w += v0.w;
    }
    // combine halves (lane ^ 32 holds the other edge stream, same slice)
    acc.x += __shfl_xor(acc.x, 32, 64);
    acc.y += __shfl_xor(acc.y, 32, 64);
    acc.z += __shfl_xor(acc.z, 32, 64);
    acc.w += __shfl_xor(acc.w, 32, 64);
    // self term + scale + bias + relu (all lanes; halves identical)
    float4 sv = *(const float4*)(hWs + (size_t)node * H_F + co);
    float s = dinv[node] / (float)(c + 1);
    float4 bv = *(const float4*)(bias + co);
    float4 o;
    o.x = fmaxf(fmaf((acc.x + sv.x), s, bv.x), 0.f);
    o.y = fmaxf(fmaf((acc.y + sv.y), s, bv.y), 0.f);
    o.z = fmaxf(fmaf((acc.z + sv.z), s, bv.z), 0.f);
    o.w = fmaxf(fmaf((acc.w + sv.w), s, bv.w), 0.f);

    if (!FUSE_OUT) {
        if (half == 0)
            *(float4*)(outp + (size_t)node * H_F + co) = o;
    } else {
        // classifier: lane owns feats 4sl..4sl+3; reduce over the 32-lane group
        float po[C_OUT];
#pragma unroll
        for (int cc = 0; cc < C_OUT; ++cc) {
            float t = o.x * Wc[(co + 0) * C_OUT + cc];
            t = fmaf(o.y, Wc[(co + 1) * C_OUT + cc], t);
            t = fmaf(o.z, Wc[(co + 2) * C_OUT + cc], t);
            po[cc] = fmaf(o.w, Wc[(co + 3) * C_OUT + cc], t);
        }
#pragma unroll
        for (int off = 16; off; off >>= 1)
#pragma unroll
            for (int cc = 0; cc < C_OUT; ++cc)
                po[cc] += __shfl_xor(po[cc], off, 64);
        if (lane == 0) {
#pragma unroll
            for (int cc = 0; cc < C_OUT; ++cc)
                outp[(size_t)node * C_OUT + cc] = po[cc] + bc[cc];
        }
    }
}

// ---------------- fp32 GEMM: C[M x 128] = (A[M x K] @ B[K x 128]) * dinv[row] ----
// 64x128 tile per 256-thread block, BK=32, 4x8 per thread.

template <int K>
__global__ __launch_bounds__(256, 4) void k_gemm(const float* __restrict__ A,
                                                 const float* __restrict__ B,
                                                 const float* __restrict__ dinv,
                                                 float* __restrict__ C) {
    __shared__ float As[32][68];
    __shared__ float Bs[32][132];
    const int tid = threadIdx.x;
    const int brow = blockIdx.x * 64;
    const int tr4 = (tid >> 4) * 4;
    const int tc4 = (tid & 15) * 4;
    const int ar  = tid >> 2;
    const int akk = (tid & 3) * 4;
    const int bqr = tid >> 5;
    const int bqc = (tid & 31) * 4;

    float acc[4][8] = {};
    const int arow_g = brow + ar;
    const bool arow_ok = arow_g < N_NODES;
    const float* Arow = A + (size_t)arow_g * K;

    for (int kt = 0; kt < K; kt += 32) {
        float4 va0 = make_float4(0.f, 0.f, 0.f, 0.f), va1 = va0;
        if (arow_ok) {
            va0 = *(const float4*)(Arow + kt + akk);
            va1 = *(const float4*)(Arow + kt + akk + 16);
        }
        As[akk + 0][ar] = va0.x;  As[akk + 1][ar] = va0.y;
        As[akk + 2][ar] = va0.z;  As[akk + 3][ar] = va0.w;
        As[akk + 16][ar] = va1.x; As[akk + 17][ar] = va1.y;
        As[akk + 18][ar] = va1.z; As[akk + 19][ar] = va1.w;
#pragma unroll
        for (int q = 0; q < 4; ++q) {
            int r = q * 8 + bqr;
            *(float4*)&Bs[r][bqc] = *(const float4*)(B + (size_t)(kt + r) * H_F + bqc);
        }
        __syncthreads();
#pragma unroll
        for (int k = 0; k < 32; ++k) {
            float4 a4 = *(const float4*)&As[k][tr4];
            float4 b0 = *(const float4*)&Bs[k][tc4];
            float4 b1 = *(const float4*)&Bs[k][tc4 + 64];
            float av[4] = {a4.x, a4.y, a4.z, a4.w};
            float bv[8] = {b0.x, b0.y, b0.z, b0.w, b1.x, b1.y, b1.z, b1.w};
#pragma unroll
            for (int i = 0; i < 4; ++i)
#pragma unroll
                for (int jj = 0; jj < 8; ++jj)
                    acc[i][jj] = fmaf(av[i], bv[jj], acc[i][jj]);
        }
        __syncthreads();
    }
#pragma unroll
    for (int i = 0; i < 4; ++i) {
        int gr = brow + tr4 + i;
        if (gr < N_NODES) {
            float dv = dinv[gr];
            float4 c0 = {acc[i][0] * dv, acc[i][1] * dv, acc[i][2] * dv, acc[i][3] * dv};
            float4 c1 = {acc[i][4] * dv, acc[i][5] * dv, acc[i][6] * dv, acc[i][7] * dv};
            *(float4*)(C + (size_t)gr * H_F + tc4) = c0;
            *(float4*)(C + (size_t)gr * H_F + tc4 + 64) = c1;
        }
    }
}

// ---------------- launch ----------------

extern "C" void kernel_launch(void* const* d_in, const int* in_sizes, int n_in,
                              void* d_out, int out_size, void* d_ws, size_t ws_size,
                              hipStream_t stream) {
    const float* x  = (const float*)d_in[0];
    const int*   ei = (const int*)d_in[1];
    const float* W1 = (const float*)d_in[2];
    const float* b1 = (const float*)d_in[3];
    const float* W2 = (const float*)d_in[4];
    const float* b2 = (const float*)d_in[5];
    const float* Wc = (const float*)d_in[6];
    const float* bc = (const float*)d_in[7];
    const int* esrc = ei;
    const int* edst = ei + E_EDGES;

    char* ws = (char*)d_ws;
    int*   cnt     = (int*)ws;                    ws += sizeof(int) * N_NODES;
    int*   row_off = (int*)ws;                    ws += sizeof(int) * N_NODES;
    int*   cursor  = (int*)ws;                    ws += sizeof(int) * N_NODES;
    float* dinv    = (float*)ws;                  ws += sizeof(float) * N_NODES;
    int*   part    = (int*)ws;                    ws += sizeof(int) * 256;
    ws = (char*)(((size_t)ws + 15) & ~(size_t)15);
    int*   csr_src = (int*)ws;                    ws += sizeof(int) * E_EDGES;
    float* bufA    = (float*)ws;                  ws += sizeof(float) * (size_t)N_NODES * H_F;
    float* bufC    = (float*)ws;
    float* out = (float*)d_out;

    const int gN = (N_NODES + 255) / 256;
    const int gE = (E_EDGES + 255) / 256;
    const int gAgg = (N_NODES + 3) / 4;
    const int gGemm = (N_NODES + 63) / 64;

    // CSR build (graph fixed per call; rebuilt every call for determinism)
    k_zero_cnt<<<gN, 256, 0, stream>>>(cnt);
    k_count<<<gE, 256, 0, stream>>>(edst, cnt);
    k_scan1<<<NB_SCAN, 256, 0, stream>>>(cnt, row_off, part);
    k_scan2<<<1, 256, 0, stream>>>(part);
    k_scan3<<<NB_SCAN, 256, 0, stream>>>(cnt, part, row_off, cursor, dinv);
    k_bucket<<<gE, 256, 0, stream>>>(esrc, edst, cursor, csr_src);

    // layer 1 (GEMM output pre-scaled by dinv)
    k_gemm<IN_F><<<gGemm, 256, 0, stream>>>(x, W1, dinv, bufA);
    k_agg<false><<<gAgg, 256, 0, stream>>>(bufA, row_off, cnt, csr_src, dinv, b1,
                                           nullptr, nullptr, bufC);

    // layer 2 (+ fused classifier)
    k_gemm<H_F><<<gGemm, 256, 0, stream>>>(bufC, W2, dinv, bufA);
    k_agg<true><<<gAgg, 256, 0, stream>>>(bufA, row_off, cnt, csr_src, dinv, b2,
                                          Wc, bc, (float*)d_out);
}

// Round 7
// 299.428 us; speedup vs baseline: 2.7250x; 1.0129x over previous
//
#include <hip/hip_runtime.h>

#define N_NODES 50000
#define E_EDGES 800000
#define IN_F 256
#define H_F 128
#define C_OUT 10
#define NB_SCAN ((N_NODES + 255) / 256)   // 196, must be <= 256
static_assert(NB_SCAN <= 256, "scan2 assumes <=256 partials");

// ---------------- CSR build: count, scan, bucket ----------------

__global__ __launch_bounds__(256) void k_count(const int* __restrict__ dst,
                                               int* __restrict__ cnt) {
    int e = blockIdx.x * 256 + threadIdx.x;
    if (e < E_EDGES) atomicAdd(&cnt[dst[e]], 1);
}

__global__ __launch_bounds__(256) void k_scan1(const int* __restrict__ cnt,
                                               int* __restrict__ row_off,
                                               int* __restrict__ part) {
    __shared__ int sm[256];
    int tid = threadIdx.x;
    int i = blockIdx.x * 256 + tid;
    int v = (i < N_NODES) ? cnt[i] : 0;
    sm[tid] = v;
    __syncthreads();
#pragma unroll
    for (int off = 1; off < 256; off <<= 1) {
        int t = (tid >= off) ? sm[tid - off] : 0;
        __syncthreads();
        sm[tid] += t;
        __syncthreads();
    }
    if (i < N_NODES) row_off[i] = sm[tid] - v;   // exclusive
    if (tid == 255) part[blockIdx.x] = sm[255];  // block total
}

__global__ __launch_bounds__(256) void k_scan2(int* __restrict__ part) {
    __shared__ int sm[256];
    int tid = threadIdx.x;
    int v = (tid < NB_SCAN) ? part[tid] : 0;
    sm[tid] = v;
    __syncthreads();
#pragma unroll
    for (int off = 1; off < 256; off <<= 1) {
        int t = (tid >= off) ? sm[tid - off] : 0;
        __syncthreads();
        sm[tid] += t;
        __syncthreads();
    }
    if (tid < NB_SCAN) part[tid] = sm[tid] - v;  // exclusive
}

__global__ __launch_bounds__(256) void k_scan3(const int* __restrict__ cnt,
                                               const int* __restrict__ part,
                                               int* __restrict__ row_off,
                                               int* __restrict__ cursor,
                                               float* __restrict__ dinv) {
    int i = blockIdx.x * 256 + threadIdx.x;
    if (i >= N_NODES) return;
    int ro = row_off[i] + part[blockIdx.x];
    row_off[i] = ro;
    cursor[i] = ro;
    dinv[i] = rsqrtf((float)(cnt[i] + 1));
}

// permute edges into CSR slots (src index only; weights folded into hW')
__global__ __launch_bounds__(256) void k_bucket(const int* __restrict__ src,
                                                const int* __restrict__ dst,
                                                int* __restrict__ cursor,
                                                int* __restrict__ csr_src) {
    int e = blockIdx.x * 256 + threadIdx.x;
    if (e >= E_EDGES) return;
    int s = src[e], d = dst[e];
    int pos = atomicAdd(&cursor[d], 1);
    csr_src[pos] = s;
}

// ---------------- fused aggregate + mean + bias + relu (+ classifier) ----------------
// hWs rows pre-scaled by dinv (GEMM epilogue). Per node:
//   o = relu( dinv[d] * (sum_edges hWs[src] + hWs[d]) / (cnt+1) + bias )
// Half-wave (32 lanes x float4 = full 128-float row) per node, 4-deep edge
// unroll -> 8 independent 512B gathers in flight per wave.

template <bool FUSE_OUT>
__global__ __launch_bounds__(256) void k_agg(const float* __restrict__ hWs,
                                             const int* __restrict__ row_off,
                                             const int* __restrict__ cnt,
                                             const int* __restrict__ csr_src,
                                             const float* __restrict__ dinv,
                                             const float* __restrict__ bias,
                                             const float* __restrict__ Wc,
                                             const float* __restrict__ bc,
                                             float* __restrict__ outp) {
    const int node = blockIdx.x * 8 + (threadIdx.x >> 5);
    if (node >= N_NODES) return;
    const int sl = threadIdx.x & 31;   // float4 slice of the row
    const int co = sl * 4;

    const int beg = row_off[node];
    const int c   = cnt[node];
    const int* ep = csr_src + beg;

    float4 acc = make_float4(0.f, 0.f, 0.f, 0.f);
    int k = 0;
    for (; k + 4 <= c; k += 4) {
        int s0 = ep[k], s1 = ep[k + 1], s2 = ep[k + 2], s3 = ep[k + 3];
        float4 v0 = *(const float4*)(hWs + (size_t)s0 * H_F + co);
        float4 v1 = *(const float4*)(hWs + (size_t)s1 * H_F + co);
        float4 v2 = *(const float4*)(hWs + (size_t)s2 * H_F + co);
        float4 v3 = *(const float4*)(hWs + (size_t)s3 * H_F + co);
        acc.x += (v0.x + v1.x) + (v2.x + v3.x);
        acc.y += (v0.y + v1.y) + (v2.y + v3.y);
        acc.z += (v0.z + v1.z) + (v2.z + v3.z);
        acc.w += (v0.w + v1.w) + (v2.w + v3.w);
    }
    for (; k < c; ++k) {
        int s0 = ep[k];
        float4 v0 = *(const float4*)(hWs + (size_t)s0 * H_F + co);
        acc.x += v0.x; acc.y += v0.y; acc.z += v0.z; acc.w += v0.w;
    }
    // self term + scale + bias + relu
    float4 sv = *(const float4*)(hWs + (size_t)node * H_F + co);
    float s = dinv[node] / (float)(c + 1);
    float4 bv = *(const float4*)(bias + co);
    float4 o;
    o.x = fmaxf(fmaf(acc.x + sv.x, s, bv.x), 0.f);
    o.y = fmaxf(fmaf(acc.y + sv.y, s, bv.y), 0.f);
    o.z = fmaxf(fmaf(acc.z + sv.z, s, bv.z), 0.f);
    o.w = fmaxf(fmaf(acc.w + sv.w, s, bv.w), 0.f);

    if (!FUSE_OUT) {
        *(float4*)(outp + (size_t)node * H_F + co) = o;
    } else {
        // classifier: lane owns feats co..co+3; reduce within the 32-lane half
        float po[C_OUT];
#pragma unroll
        for (int cc = 0; cc < C_OUT; ++cc) {
            float t = o.x * Wc[(co + 0) * C_OUT + cc];
            t = fmaf(o.y, Wc[(co + 1) * C_OUT + cc], t);
            t = fmaf(o.z, Wc[(co + 2) * C_OUT + cc], t);
            po[cc] = fmaf(o.w, Wc[(co + 3) * C_OUT + cc], t);
        }
#pragma unroll
        for (int off = 16; off; off >>= 1)
#pragma unroll
            for (int cc = 0; cc < C_OUT; ++cc)
                po[cc] += __shfl_xor(po[cc], off, 64);   // offsets <32 stay in-half
        if (sl == 0) {
#pragma unroll
            for (int cc = 0; cc < C_OUT; ++cc)
                outp[(size_t)node * C_OUT + cc] = po[cc] + bc[cc];
        }
    }
}

// ---------------- fp32 GEMM: C[M x 128] = (A[M x K] @ B[K x 128]) * dinv[row] ----
// 64x128 tile per 256-thread block, BK=32, 4x8 per thread.

template <int K>
__global__ __launch_bounds__(256, 4) void k_gemm(const float* __restrict__ A,
                                                 const float* __restrict__ B,
                                                 const float* __restrict__ dinv,
                                                 float* __restrict__ C) {
    __shared__ float As[32][68];
    __shared__ float Bs[32][132];
    const int tid = threadIdx.x;
    const int brow = blockIdx.x * 64;
    const int tr4 = (tid >> 4) * 4;
    const int tc4 = (tid & 15) * 4;
    const int ar  = tid >> 2;
    const int akk = (tid & 3) * 4;
    const int bqr = tid >> 5;
    const int bqc = (tid & 31) * 4;

    float acc[4][8] = {};
    const int arow_g = brow + ar;
    const bool arow_ok = arow_g < N_NODES;
    const float* Arow = A + (size_t)arow_g * K;

    for (int kt = 0; kt < K; kt += 32) {
        float4 va0 = make_float4(0.f, 0.f, 0.f, 0.f), va1 = va0;
        if (arow_ok) {
            va0 = *(const float4*)(Arow + kt + akk);
            va1 = *(const float4*)(Arow + kt + akk + 16);
        }
        As[akk + 0][ar] = va0.x;  As[akk + 1][ar] = va0.y;
        As[akk + 2][ar] = va0.z;  As[akk + 3][ar] = va0.w;
        As[akk + 16][ar] = va1.x; As[akk + 17][ar] = va1.y;
        As[akk + 18][ar] = va1.z; As[akk + 19][ar] = va1.w;
#pragma unroll
        for (int q = 0; q < 4; ++q) {
            int r = q * 8 + bqr;
            *(float4*)&Bs[r][bqc] = *(const float4*)(B + (size_t)(kt + r) * H_F + bqc);
        }
        __syncthreads();
#pragma unroll
        for (int k = 0; k < 32; ++k) {
            float4 a4 = *(const float4*)&As[k][tr4];
            float4 b0 = *(const float4*)&Bs[k][tc4];
            float4 b1 = *(const float4*)&Bs[k][tc4 + 64];
            float av[4] = {a4.x, a4.y, a4.z, a4.w};
            float bv[8] = {b0.x, b0.y, b0.z, b0.w, b1.x, b1.y, b1.z, b1.w};
#pragma unroll
            for (int i = 0; i < 4; ++i)
#pragma unroll
                for (int jj = 0; jj < 8; ++jj)
                    acc[i][jj] = fmaf(av[i], bv[jj], acc[i][jj]);
        }
        __syncthreads();
    }
#pragma unroll
    for (int i = 0; i < 4; ++i) {
        int gr = brow + tr4 + i;
        if (gr < N_NODES) {
            float dv = dinv[gr];
            float4 c0 = {acc[i][0] * dv, acc[i][1] * dv, acc[i][2] * dv, acc[i][3] * dv};
            float4 c1 = {acc[i][4] * dv, acc[i][5] * dv, acc[i][6] * dv, acc[i][7] * dv};
            *(float4*)(C + (size_t)gr * H_F + tc4) = c0;
            *(float4*)(C + (size_t)gr * H_F + tc4 + 64) = c1;
        }
    }
}

// ---------------- launch ----------------

extern "C" void kernel_launch(void* const* d_in, const int* in_sizes, int n_in,
                              void* d_out, int out_size, void* d_ws, size_t ws_size,
                              hipStream_t stream) {
    const float* x  = (const float*)d_in[0];
    const int*   ei = (const int*)d_in[1];
    const float* W1 = (const float*)d_in[2];
    const float* b1 = (const float*)d_in[3];
    const float* W2 = (const float*)d_in[4];
    const float* b2 = (const float*)d_in[5];
    const float* Wc = (const float*)d_in[6];
    const float* bc = (const float*)d_in[7];
    const int* esrc = ei;
    const int* edst = ei + E_EDGES;

    char* ws = (char*)d_ws;
    int*   cnt     = (int*)ws;                    ws += sizeof(int) * N_NODES;
    int*   row_off = (int*)ws;                    ws += sizeof(int) * N_NODES;
    int*   cursor  = (int*)ws;                    ws += sizeof(int) * N_NODES;
    float* dinv    = (float*)ws;                  ws += sizeof(float) * N_NODES;
    int*   part    = (int*)ws;                    ws += sizeof(int) * 256;
    ws = (char*)(((size_t)ws + 15) & ~(size_t)15);
    int*   csr_src = (int*)ws;                    ws += sizeof(int) * E_EDGES;
    float* bufA    = (float*)ws;                  ws += sizeof(float) * (size_t)N_NODES * H_F;
    float* bufC    = (float*)ws;

    const int gE = (E_EDGES + 255) / 256;
    const int gAgg = (N_NODES + 7) / 8;
    const int gGemm = (N_NODES + 63) / 64;

    // CSR build (graph fixed per call; rebuilt every call for determinism)
    hipMemsetAsync(cnt, 0, sizeof(int) * N_NODES, stream);
    k_count<<<gE, 256, 0, stream>>>(edst, cnt);
    k_scan1<<<NB_SCAN, 256, 0, stream>>>(cnt, row_off, part);
    k_scan2<<<1, 256, 0, stream>>>(part);
    k_scan3<<<NB_SCAN, 256, 0, stream>>>(cnt, part, row_off, cursor, dinv);
    k_bucket<<<gE, 256, 0, stream>>>(esrc, edst, cursor, csr_src);

    // layer 1 (GEMM output pre-scaled by dinv)
    k_gemm<IN_F><<<gGemm, 256, 0, stream>>>(x, W1, dinv, bufA);
    k_agg<false><<<gAgg, 256, 0, stream>>>(bufA, row_off, cnt, csr_src, dinv, b1,
                                           nullptr, nullptr, bufC);

    // layer 2 (+ fused classifier)
    k_gemm<H_F><<<gGemm, 256, 0, stream>>>(bufC, W2, dinv, bufA);
    k_agg<true><<<gAgg, 256, 0, stream>>>(bufA, row_off, cnt, csr_src, dinv, b2,
                                          Wc, bc, (float*)d_out);
}

// Round 8
// 252.728 us; speedup vs baseline: 3.2286x; 1.1848x over previous
//
#include <hip/hip_runtime.h>

#define N_NODES 50000
#define E_EDGES 800000
#define IN_F 256
#define H_F 128
#define C_OUT 10
#define NB_SCAN ((N_NODES + 255) / 256)   // 196, must be <= 256
static_assert(NB_SCAN <= 256, "scan2 assumes <=256 partials");

typedef __attribute__((ext_vector_type(4))) float f32x4;
typedef __attribute__((ext_vector_type(8))) short s16x8;

__device__ __forceinline__ unsigned short f2bf_rne(float x) {
    unsigned u = __float_as_uint(x);
    u = (u + 0x7FFFu + ((u >> 16) & 1u)) >> 16;
    return (unsigned short)u;
}
__device__ __forceinline__ float bf2f(unsigned short h) {
    return __uint_as_float(((unsigned)h) << 16);
}

// ---------------- CSR build: count, scan, bucket ----------------

__global__ __launch_bounds__(256) void k_count(const int* __restrict__ dst,
                                               int* __restrict__ cnt) {
    int e = blockIdx.x * 256 + threadIdx.x;
    if (e < E_EDGES) atomicAdd(&cnt[dst[e]], 1);
}

__global__ __launch_bounds__(256) void k_scan1(const int* __restrict__ cnt,
                                               int* __restrict__ row_off,
                                               int* __restrict__ part) {
    __shared__ int sm[256];
    int tid = threadIdx.x;
    int i = blockIdx.x * 256 + tid;
    int v = (i < N_NODES) ? cnt[i] : 0;
    sm[tid] = v;
    __syncthreads();
#pragma unroll
    for (int off = 1; off < 256; off <<= 1) {
        int t = (tid >= off) ? sm[tid - off] : 0;
        __syncthreads();
        sm[tid] += t;
        __syncthreads();
    }
    if (i < N_NODES) row_off[i] = sm[tid] - v;   // exclusive
    if (tid == 255) part[blockIdx.x] = sm[255];  // block total
}

__global__ __launch_bounds__(256) void k_scan2(int* __restrict__ part) {
    __shared__ int sm[256];
    int tid = threadIdx.x;
    int v = (tid < NB_SCAN) ? part[tid] : 0;
    sm[tid] = v;
    __syncthreads();
#pragma unroll
    for (int off = 1; off < 256; off <<= 1) {
        int t = (tid >= off) ? sm[tid - off] : 0;
        __syncthreads();
        sm[tid] += t;
        __syncthreads();
    }
    if (tid < NB_SCAN) part[tid] = sm[tid] - v;  // exclusive
}

__global__ __launch_bounds__(256) void k_scan3(const int* __restrict__ cnt,
                                               const int* __restrict__ part,
                                               int* __restrict__ row_off,
                                               int* __restrict__ cursor,
                                               float* __restrict__ dinv) {
    int i = blockIdx.x * 256 + threadIdx.x;
    if (i >= N_NODES) return;
    int ro = row_off[i] + part[blockIdx.x];
    row_off[i] = ro;
    cursor[i] = ro;
    dinv[i] = rsqrtf((float)(cnt[i] + 1));
}

__global__ __launch_bounds__(256) void k_bucket(const int* __restrict__ src,
                                                const int* __restrict__ dst,
                                                int* __restrict__ cursor,
                                                int* __restrict__ csr_src) {
    int e = blockIdx.x * 256 + threadIdx.x;
    if (e >= E_EDGES) return;
    int s = src[e], d = dst[e];
    int pos = atomicAdd(&cursor[d], 1);
    csr_src[pos] = s;
}

// ---------------- pre-pack W1/W2 into MFMA fragment-image (bf16 hi/lo) -------
// Fragment image: [kt][nb][lane][j] ushort, lane=(n&15)+16*((k&31)>>3), j=k&7.

__global__ __launch_bounds__(256) void k_convB(const float* __restrict__ W1,
                                               const float* __restrict__ W2,
                                               unsigned short* __restrict__ B1h,
                                               unsigned short* __restrict__ B1l,
                                               unsigned short* __restrict__ B2h,
                                               unsigned short* __restrict__ B2l) {
    int id = blockIdx.x * 256 + threadIdx.x;
    const float* W;
    unsigned short *Bh, *Bl;
    int k, n;
    if (id < IN_F * H_F) {
        W = W1; Bh = B1h; Bl = B1l;
        k = id >> 7; n = id & 127;
    } else {
        id -= IN_F * H_F;
        if (id >= H_F * H_F) return;
        W = W2; Bh = B2h; Bl = B2l;
        k = id >> 7; n = id & 127;
    }
    float x = W[(size_t)k * H_F + n];
    unsigned short h = f2bf_rne(x);
    unsigned short l = f2bf_rne(x - bf2f(h));
    int kt = k >> 5, kg = (k & 31) >> 3, j = k & 7;
    int lane = (n & 15) + 16 * kg, nb = n >> 4;
    size_t idx = (((size_t)kt * 8 + nb) * 64 + lane) * 8 + j;
    Bh[idx] = h;
    Bl[idx] = l;
}

// ---------------- MFMA GEMM: C[M x 128] = (A[M x K] @ W[K x 128]) * dinv ------
// bf16x3 split (hi*hi + hi*lo + lo*hi), fp32 accumulate. 128x128 tile,
// 4 waves x (2 m-frags x 8 n-frags), BK=32.

template <int K>
__global__ __launch_bounds__(256) void k_gemm_mfma(const float* __restrict__ A,
                                                   const unsigned short* __restrict__ Bh_img,
                                                   const unsigned short* __restrict__ Bl_img,
                                                   const float* __restrict__ dinv,
                                                   float* __restrict__ C) {
    __shared__ unsigned short Ah[8 * 64 * 8];   // [mb][lane][j]
    __shared__ unsigned short Al[8 * 64 * 8];
    __shared__ unsigned short Bh[8 * 64 * 8];   // [nb][lane][j]
    __shared__ unsigned short Bl[8 * 64 * 8];

    const int tid  = threadIdx.x;
    const int w    = tid >> 6;
    const int lane = tid & 63;
    const int brow = blockIdx.x * 128;

    const int ar  = tid >> 1;          // A-stage row 0..127
    const int akq = tid & 1;           // k-half (16 floats)
    const int arow_l = min(brow + ar, N_NODES - 1);
    const float* Arow = A + (size_t)arow_l * K;
    const int amb = ar >> 4;
    const int ar15 = ar & 15;

    f32x4 acc[2][8] = {};

    for (int kt = 0; kt < K; kt += 32) {
        // stage A: 4x float4 per thread, convert to bf16 hi/lo
#pragma unroll
        for (int i = 0; i < 4; ++i) {
            int k0 = akq * 16 + i * 4;           // 0..28, step 4
            float4 v = *(const float4*)(Arow + kt + k0);
            unsigned short h0 = f2bf_rne(v.x), h1 = f2bf_rne(v.y);
            unsigned short h2 = f2bf_rne(v.z), h3 = f2bf_rne(v.w);
            unsigned short l0 = f2bf_rne(v.x - bf2f(h0));
            unsigned short l1 = f2bf_rne(v.y - bf2f(h1));
            unsigned short l2 = f2bf_rne(v.z - bf2f(h2));
            unsigned short l3 = f2bf_rne(v.w - bf2f(h3));
            int kg = k0 >> 3, j0 = k0 & 7;       // j0 in {0,4}
            int idx = ((amb * 64) + ar15 + 16 * kg) * 8 + j0;
            *(uint2*)&Ah[idx] = make_uint2((unsigned)h0 | ((unsigned)h1 << 16),
                                           (unsigned)h2 | ((unsigned)h3 << 16));
            *(uint2*)&Al[idx] = make_uint2((unsigned)l0 | ((unsigned)l1 << 16),
                                           (unsigned)l2 | ((unsigned)l3 << 16));
        }
        // stage B: copy 8 KB hi + 8 KB lo from pre-packed image
        {
            const uint4* sh = (const uint4*)(Bh_img + (size_t)(kt >> 5) * 4096);
            const uint4* sl = (const uint4*)(Bl_img + (size_t)(kt >> 5) * 4096);
            ((uint4*)Bh)[tid * 2]     = sh[tid * 2];
            ((uint4*)Bh)[tid * 2 + 1] = sh[tid * 2 + 1];
            ((uint4*)Bl)[tid * 2]     = sl[tid * 2];
            ((uint4*)Bl)[tid * 2 + 1] = sl[tid * 2 + 1];
        }
        __syncthreads();

        const int mb0 = w * 2, mb1 = w * 2 + 1;
        s16x8 a0h = *(const s16x8*)&Ah[(mb0 * 64 + lane) * 8];
        s16x8 a0l = *(const s16x8*)&Al[(mb0 * 64 + lane) * 8];
        s16x8 a1h = *(const s16x8*)&Ah[(mb1 * 64 + lane) * 8];
        s16x8 a1l = *(const s16x8*)&Al[(mb1 * 64 + lane) * 8];
#pragma unroll
        for (int nb = 0; nb < 8; ++nb) {
            s16x8 bh = *(const s16x8*)&Bh[(nb * 64 + lane) * 8];
            s16x8 bl = *(const s16x8*)&Bl[(nb * 64 + lane) * 8];
            acc[0][nb] = __builtin_amdgcn_mfma_f32_16x16x32_bf16(a0h, bh, acc[0][nb], 0, 0, 0);
            acc[0][nb] = __builtin_amdgcn_mfma_f32_16x16x32_bf16(a0h, bl, acc[0][nb], 0, 0, 0);
            acc[0][nb] = __builtin_amdgcn_mfma_f32_16x16x32_bf16(a0l, bh, acc[0][nb], 0, 0, 0);
            acc[1][nb] = __builtin_amdgcn_mfma_f32_16x16x32_bf16(a1h, bh, acc[1][nb], 0, 0, 0);
            acc[1][nb] = __builtin_amdgcn_mfma_f32_16x16x32_bf16(a1h, bl, acc[1][nb], 0, 0, 0);
            acc[1][nb] = __builtin_amdgcn_mfma_f32_16x16x32_bf16(a1l, bh, acc[1][nb], 0, 0, 0);
        }
        __syncthreads();
    }

    // epilogue: C/D layout col = lane&15, row = (lane>>4)*4 + reg  [m89/m91]
    const int col = lane & 15;
    const int rg4 = (lane >> 4) * 4;
#pragma unroll
    for (int mb = 0; mb < 2; ++mb) {
#pragma unroll
        for (int reg = 0; reg < 4; ++reg) {
            int gr = brow + (w * 2 + mb) * 16 + rg4 + reg;
            if (gr < N_NODES) {
                float dv = dinv[gr];
#pragma unroll
                for (int nb = 0; nb < 8; ++nb)
                    C[(size_t)gr * H_F + nb * 16 + col] = acc[mb][nb][reg] * dv;
            }
        }
    }
}

// ---------------- fused aggregate + mean + bias + relu (+ classifier) --------
// hWs rows pre-scaled by dinv. o = relu( dinv[d]*(sum hWs[src] + hWs[d])/(c+1) + b )
// Half-wave (32 lanes x float4 = 128-float row) per node, 4-deep edge unroll.

template <bool FUSE_OUT>
__global__ __launch_bounds__(256) void k_agg(const float* __restrict__ hWs,
                                             const int* __restrict__ row_off,
                                             const int* __restrict__ cnt,
                                             const int* __restrict__ csr_src,
                                             const float* __restrict__ dinv,
                                             const float* __restrict__ bias,
                                             const float* __restrict__ Wc,
                                             const float* __restrict__ bc,
                                             float* __restrict__ outp) {
    const int node = blockIdx.x * 8 + (threadIdx.x >> 5);
    if (node >= N_NODES) return;
    const int sl = threadIdx.x & 31;
    const int co = sl * 4;

    const int beg = row_off[node];
    const int c   = cnt[node];
    const int* ep = csr_src + beg;

    float4 acc = make_float4(0.f, 0.f, 0.f, 0.f);
    int k = 0;
    for (; k + 4 <= c; k += 4) {
        int s0 = ep[k], s1 = ep[k + 1], s2 = ep[k + 2], s3 = ep[k + 3];
        float4 v0 = *(const float4*)(hWs + (size_t)s0 * H_F + co);
        float4 v1 = *(const float4*)(hWs + (size_t)s1 * H_F + co);
        float4 v2 = *(const float4*)(hWs + (size_t)s2 * H_F + co);
        float4 v3 = *(const float4*)(hWs + (size_t)s3 * H_F + co);
        acc.x += (v0.x + v1.x) + (v2.x + v3.x);
        acc.y += (v0.y + v1.y) + (v2.y + v3.y);
        acc.z += (v0.z + v1.z) + (v2.z + v3.z);
        acc.w += (v0.w + v1.w) + (v2.w + v3.w);
    }
    for (; k < c; ++k) {
        int s0 = ep[k];
        float4 v0 = *(const float4*)(hWs + (size_t)s0 * H_F + co);
        acc.x += v0.x; acc.y += v0.y; acc.z += v0.z; acc.w += v0.w;
    }
    float4 sv = *(const float4*)(hWs + (size_t)node * H_F + co);
    float s = dinv[node] / (float)(c + 1);
    float4 bv = *(const float4*)(bias + co);
    float4 o;
    o.x = fmaxf(fmaf(acc.x + sv.x, s, bv.x), 0.f);
    o.y = fmaxf(fmaf(acc.y + sv.y, s, bv.y), 0.f);
    o.z = fmaxf(fmaf(acc.z + sv.z, s, bv.z), 0.f);
    o.w = fmaxf(fmaf(acc.w + sv.w, s, bv.w), 0.f);

    if (!FUSE_OUT) {
        *(float4*)(outp + (size_t)node * H_F + co) = o;
    } else {
        float po[C_OUT];
#pragma unroll
        for (int cc = 0; cc < C_OUT; ++cc) {
            float t = o.x * Wc[(co + 0) * C_OUT + cc];
            t = fmaf(o.y, Wc[(co + 1) * C_OUT + cc], t);
            t = fmaf(o.z, Wc[(co + 2) * C_OUT + cc], t);
            po[cc] = fmaf(o.w, Wc[(co + 3) * C_OUT + cc], t);
        }
#pragma unroll
        for (int off = 16; off; off >>= 1)
#pragma unroll
            for (int cc = 0; cc < C_OUT; ++cc)
                po[cc] += __shfl_xor(po[cc], off, 64);   // offsets <32 stay in-half
        if (sl == 0) {
#pragma unroll
            for (int cc = 0; cc < C_OUT; ++cc)
                outp[(size_t)node * C_OUT + cc] = po[cc] + bc[cc];
        }
    }
}

// ---------------- launch ----------------

extern "C" void kernel_launch(void* const* d_in, const int* in_sizes, int n_in,
                              void* d_out, int out_size, void* d_ws, size_t ws_size,
                              hipStream_t stream) {
    const float* x  = (const float*)d_in[0];
    const int*   ei = (const int*)d_in[1];
    const float* W1 = (const float*)d_in[2];
    const float* b1 = (const float*)d_in[3];
    const float* W2 = (const float*)d_in[4];
    const float* b2 = (const float*)d_in[5];
    const float* Wc = (const float*)d_in[6];
    const float* bc = (const float*)d_in[7];
    const int* esrc = ei;
    const int* edst = ei + E_EDGES;

    char* ws = (char*)d_ws;
    int*   cnt     = (int*)ws;                    ws += sizeof(int) * N_NODES;
    int*   row_off = (int*)ws;                    ws += sizeof(int) * N_NODES;
    int*   cursor  = (int*)ws;                    ws += sizeof(int) * N_NODES;
    float* dinv    = (float*)ws;                  ws += sizeof(float) * N_NODES;
    int*   part    = (int*)ws;                    ws += sizeof(int) * 256;
    ws = (char*)(((size_t)ws + 15) & ~(size_t)15);
    int*   csr_src = (int*)ws;                    ws += sizeof(int) * E_EDGES;
    unsigned short* B1h = (unsigned short*)ws;    ws += sizeof(short) * IN_F * H_F;
    unsigned short* B1l = (unsigned short*)ws;    ws += sizeof(short) * IN_F * H_F;
    unsigned short* B2h = (unsigned short*)ws;    ws += sizeof(short) * H_F * H_F;
    unsigned short* B2l = (unsigned short*)ws;    ws += sizeof(short) * H_F * H_F;
    float* bufA    = (float*)ws;                  ws += sizeof(float) * (size_t)N_NODES * H_F;
    float* bufC    = (float*)ws;

    const int gE = (E_EDGES + 255) / 256;
    const int gAgg = (N_NODES + 7) / 8;
    const int gGemm = (N_NODES + 127) / 128;
    const int gConv = (IN_F * H_F + H_F * H_F + 255) / 256;

    // CSR build (graph fixed per call; rebuilt every call for determinism)
    hipMemsetAsync(cnt, 0, sizeof(int) * N_NODES, stream);
    k_count<<<gE, 256, 0, stream>>>(edst, cnt);
    k_scan1<<<NB_SCAN, 256, 0, stream>>>(cnt, row_off, part);
    k_scan2<<<1, 256, 0, stream>>>(part);
    k_scan3<<<NB_SCAN, 256, 0, stream>>>(cnt, part, row_off, cursor, dinv);
    k_bucket<<<gE, 256, 0, stream>>>(esrc, edst, cursor, csr_src);
    k_convB<<<gConv, 256, 0, stream>>>(W1, W2, B1h, B1l, B2h, B2l);

    // layer 1 (GEMM output pre-scaled by dinv)
    k_gemm_mfma<IN_F><<<gGemm, 256, 0, stream>>>(x, B1h, B1l, dinv, bufA);
    k_agg<false><<<gAgg, 256, 0, stream>>>(bufA, row_off, cnt, csr_src, dinv, b1,
                                           nullptr, nullptr, bufC);

    // layer 2 (+ fused classifier)
    k_gemm_mfma<H_F><<<gGemm, 256, 0, stream>>>(bufC, B2h, B2l, dinv, bufA);
    k_agg<true><<<gAgg, 256, 0, stream>>>(bufA, row_off, cnt, csr_src, dinv, b2,
                                          Wc, bc, (float*)d_out);
}

// Round 9
// 214.084 us; speedup vs baseline: 3.8113x; 1.1805x over previous
//
#include <hip/hip_runtime.h>

#define N_NODES 50000
#define E_EDGES 800000
#define IN_F 256
#define H_F 128
#define C_OUT 10
#define NB_SCAN ((N_NODES + 255) / 256)   // 196, must be <= 256
static_assert(NB_SCAN <= 256, "scan2 assumes <=256 partials");

typedef __attribute__((ext_vector_type(4))) float f32x4;
typedef __attribute__((ext_vector_type(8))) short s16x8;

__device__ __forceinline__ unsigned short f2bf_rne(float x) {
    unsigned u = __float_as_uint(x);
    u = (u + 0x7FFFu + ((u >> 16) & 1u)) >> 16;
    return (unsigned short)u;
}
__device__ __forceinline__ float bf2f(unsigned short h) {
    return __uint_as_float(((unsigned)h) << 16);
}

// ---------------- CSR build: count, scan, bucket ----------------

__global__ __launch_bounds__(256) void k_count(const int* __restrict__ dst,
                                               int* __restrict__ cnt) {
    int e = blockIdx.x * 256 + threadIdx.x;
    if (e < E_EDGES) atomicAdd(&cnt[dst[e]], 1);
}

__global__ __launch_bounds__(256) void k_scan1(const int* __restrict__ cnt,
                                               int* __restrict__ row_off,
                                               int* __restrict__ part) {
    __shared__ int sm[256];
    int tid = threadIdx.x;
    int i = blockIdx.x * 256 + tid;
    int v = (i < N_NODES) ? cnt[i] : 0;
    sm[tid] = v;
    __syncthreads();
#pragma unroll
    for (int off = 1; off < 256; off <<= 1) {
        int t = (tid >= off) ? sm[tid - off] : 0;
        __syncthreads();
        sm[tid] += t;
        __syncthreads();
    }
    if (i < N_NODES) row_off[i] = sm[tid] - v;   // exclusive
    if (tid == 255) part[blockIdx.x] = sm[255];  // block total
}

__global__ __launch_bounds__(256) void k_scan2(int* __restrict__ part) {
    __shared__ int sm[256];
    int tid = threadIdx.x;
    int v = (tid < NB_SCAN) ? part[tid] : 0;
    sm[tid] = v;
    __syncthreads();
#pragma unroll
    for (int off = 1; off < 256; off <<= 1) {
        int t = (tid >= off) ? sm[tid - off] : 0;
        __syncthreads();
        sm[tid] += t;
        __syncthreads();
    }
    if (tid < NB_SCAN) part[tid] = sm[tid] - v;  // exclusive
}

__global__ __launch_bounds__(256) void k_scan3(const int* __restrict__ cnt,
                                               const int* __restrict__ part,
                                               int* __restrict__ row_off,
                                               int* __restrict__ cursor,
                                               float* __restrict__ dinv) {
    int i = blockIdx.x * 256 + threadIdx.x;
    if (i >= N_NODES) return;
    int ro = row_off[i] + part[blockIdx.x];
    row_off[i] = ro;
    cursor[i] = ro;
    dinv[i] = rsqrtf((float)(cnt[i] + 1));
}

__global__ __launch_bounds__(256) void k_bucket(const int* __restrict__ src,
                                                const int* __restrict__ dst,
                                                int* __restrict__ cursor,
                                                int* __restrict__ csr_src) {
    int e = blockIdx.x * 256 + threadIdx.x;
    if (e >= E_EDGES) return;
    int s = src[e], d = dst[e];
    int pos = atomicAdd(&cursor[d], 1);
    csr_src[pos] = s;
}

// ---------------- pre-pack W1/W2 into MFMA fragment-image (bf16 hi/lo) -------
// Fragment image: [kt][nb][lane][j] ushort, lane=(n&15)+16*((k&31)>>3), j=k&7.

__global__ __launch_bounds__(256) void k_convB(const float* __restrict__ W1,
                                               const float* __restrict__ W2,
                                               unsigned short* __restrict__ B1h,
                                               unsigned short* __restrict__ B1l,
                                               unsigned short* __restrict__ B2h,
                                               unsigned short* __restrict__ B2l) {
    int id = blockIdx.x * 256 + threadIdx.x;
    const float* W;
    unsigned short *Bh, *Bl;
    int k, n;
    if (id < IN_F * H_F) {
        W = W1; Bh = B1h; Bl = B1l;
        k = id >> 7; n = id & 127;
    } else {
        id -= IN_F * H_F;
        if (id >= H_F * H_F) return;
        W = W2; Bh = B2h; Bl = B2l;
        k = id >> 7; n = id & 127;
    }
    float x = W[(size_t)k * H_F + n];
    unsigned short h = f2bf_rne(x);
    unsigned short l = f2bf_rne(x - bf2f(h));
    int kt = k >> 5, kg = (k & 31) >> 3, j = k & 7;
    int lane = (n & 15) + 16 * kg, nb = n >> 4;
    size_t idx = (((size_t)kt * 8 + nb) * 64 + lane) * 8 + j;
    Bh[idx] = h;
    Bl[idx] = l;
}

// ---------------- MFMA GEMM: tab[M x 128] = bf16((A[M x K] @ W[K x 128])*dinv) --
// bf16x3 split (hi*hi + hi*lo + lo*hi), fp32 accumulate. 128x128 tile,
// 4 waves x (2 m-frags x 8 n-frags), BK=32. Output is the bf16 gather table.

template <int K>
__global__ __launch_bounds__(256) void k_gemm_mfma(const float* __restrict__ A,
                                                   const unsigned short* __restrict__ Bh_img,
                                                   const unsigned short* __restrict__ Bl_img,
                                                   const float* __restrict__ dinv,
                                                   unsigned short* __restrict__ tab) {
    __shared__ unsigned short Ah[8 * 64 * 8];   // [mb][lane][j]
    __shared__ unsigned short Al[8 * 64 * 8];
    __shared__ unsigned short Bh[8 * 64 * 8];   // [nb][lane][j]
    __shared__ unsigned short Bl[8 * 64 * 8];

    const int tid  = threadIdx.x;
    const int w    = tid >> 6;
    const int lane = tid & 63;
    const int brow = blockIdx.x * 128;

    const int ar  = tid >> 1;          // A-stage row 0..127
    const int akq = tid & 1;           // k-half (16 floats)
    const int arow_l = min(brow + ar, N_NODES - 1);
    const float* Arow = A + (size_t)arow_l * K;
    const int amb = ar >> 4;
    const int ar15 = ar & 15;

    f32x4 acc[2][8] = {};

    for (int kt = 0; kt < K; kt += 32) {
        // stage A: 4x float4 per thread, convert to bf16 hi/lo
#pragma unroll
        for (int i = 0; i < 4; ++i) {
            int k0 = akq * 16 + i * 4;           // 0..28, step 4
            float4 v = *(const float4*)(Arow + kt + k0);
            unsigned short h0 = f2bf_rne(v.x), h1 = f2bf_rne(v.y);
            unsigned short h2 = f2bf_rne(v.z), h3 = f2bf_rne(v.w);
            unsigned short l0 = f2bf_rne(v.x - bf2f(h0));
            unsigned short l1 = f2bf_rne(v.y - bf2f(h1));
            unsigned short l2 = f2bf_rne(v.z - bf2f(h2));
            unsigned short l3 = f2bf_rne(v.w - bf2f(h3));
            int kg = k0 >> 3, j0 = k0 & 7;       // j0 in {0,4}
            int idx = ((amb * 64) + ar15 + 16 * kg) * 8 + j0;
            *(uint2*)&Ah[idx] = make_uint2((unsigned)h0 | ((unsigned)h1 << 16),
                                           (unsigned)h2 | ((unsigned)h3 << 16));
            *(uint2*)&Al[idx] = make_uint2((unsigned)l0 | ((unsigned)l1 << 16),
                                           (unsigned)l2 | ((unsigned)l3 << 16));
        }
        // stage B: copy 8 KB hi + 8 KB lo from pre-packed image
        {
            const uint4* sh = (const uint4*)(Bh_img + (size_t)(kt >> 5) * 4096);
            const uint4* sl = (const uint4*)(Bl_img + (size_t)(kt >> 5) * 4096);
            ((uint4*)Bh)[tid * 2]     = sh[tid * 2];
            ((uint4*)Bh)[tid * 2 + 1] = sh[tid * 2 + 1];
            ((uint4*)Bl)[tid * 2]     = sl[tid * 2];
            ((uint4*)Bl)[tid * 2 + 1] = sl[tid * 2 + 1];
        }
        __syncthreads();

        const int mb0 = w * 2, mb1 = w * 2 + 1;
        s16x8 a0h = *(const s16x8*)&Ah[(mb0 * 64 + lane) * 8];
        s16x8 a0l = *(const s16x8*)&Al[(mb0 * 64 + lane) * 8];
        s16x8 a1h = *(const s16x8*)&Ah[(mb1 * 64 + lane) * 8];
        s16x8 a1l = *(const s16x8*)&Al[(mb1 * 64 + lane) * 8];
#pragma unroll
        for (int nb = 0; nb < 8; ++nb) {
            s16x8 bh = *(const s16x8*)&Bh[(nb * 64 + lane) * 8];
            s16x8 bl = *(const s16x8*)&Bl[(nb * 64 + lane) * 8];
            acc[0][nb] = __builtin_amdgcn_mfma_f32_16x16x32_bf16(a0h, bh, acc[0][nb], 0, 0, 0);
            acc[0][nb] = __builtin_amdgcn_mfma_f32_16x16x32_bf16(a0h, bl, acc[0][nb], 0, 0, 0);
            acc[0][nb] = __builtin_amdgcn_mfma_f32_16x16x32_bf16(a0l, bh, acc[0][nb], 0, 0, 0);
            acc[1][nb] = __builtin_amdgcn_mfma_f32_16x16x32_bf16(a1h, bh, acc[1][nb], 0, 0, 0);
            acc[1][nb] = __builtin_amdgcn_mfma_f32_16x16x32_bf16(a1h, bl, acc[1][nb], 0, 0, 0);
            acc[1][nb] = __builtin_amdgcn_mfma_f32_16x16x32_bf16(a1l, bh, acc[1][nb], 0, 0, 0);
        }
        __syncthreads();
    }

    // epilogue: C/D layout col = lane&15, row = (lane>>4)*4 + reg  [m89/m91]
    const int col = lane & 15;
    const int rg4 = (lane >> 4) * 4;
#pragma unroll
    for (int mb = 0; mb < 2; ++mb) {
#pragma unroll
        for (int reg = 0; reg < 4; ++reg) {
            int gr = brow + (w * 2 + mb) * 16 + rg4 + reg;
            if (gr < N_NODES) {
                float dv = dinv[gr];
#pragma unroll
                for (int nb = 0; nb < 8; ++nb)
                    tab[(size_t)gr * H_F + nb * 16 + col] =
                        f2bf_rne(acc[mb][nb][reg] * dv);
            }
        }
    }
}

// ---------------- fused aggregate + mean + bias + relu (+ classifier) --------
// tab rows are bf16, pre-scaled by dinv. Per node:
//   o = relu( dinv[d] * (sum_edges tab[src] + tab[d]) / (cnt+1) + bias )
// Half-wave (32 lanes x 4 bf16 = 128-feat row) per node, 4-deep edge unroll.
// fp32 accumulate; only the gathered operand is bf16.

template <bool FUSE_OUT>
__global__ __launch_bounds__(256) void k_agg(const unsigned short* __restrict__ tab,
                                             const int* __restrict__ row_off,
                                             const int* __restrict__ cnt,
                                             const int* __restrict__ csr_src,
                                             const float* __restrict__ dinv,
                                             const float* __restrict__ bias,
                                             const float* __restrict__ Wc,
                                             const float* __restrict__ bc,
                                             float* __restrict__ outp) {
    const int node = blockIdx.x * 8 + (threadIdx.x >> 5);
    if (node >= N_NODES) return;
    const int sl = threadIdx.x & 31;
    const int co = sl * 4;             // bf16 feature base

    const int beg = row_off[node];
    const int c   = cnt[node];
    const int* ep = csr_src + beg;

    float4 acc = make_float4(0.f, 0.f, 0.f, 0.f);
    int k = 0;
    for (; k + 4 <= c; k += 4) {
        int s0 = ep[k], s1 = ep[k + 1], s2 = ep[k + 2], s3 = ep[k + 3];
        uint2 u0 = *(const uint2*)(tab + (size_t)s0 * H_F + co);
        uint2 u1 = *(const uint2*)(tab + (size_t)s1 * H_F + co);
        uint2 u2 = *(const uint2*)(tab + (size_t)s2 * H_F + co);
        uint2 u3 = *(const uint2*)(tab + (size_t)s3 * H_F + co);
        acc.x += __uint_as_float(u0.x << 16) + __uint_as_float(u1.x << 16)
               + __uint_as_float(u2.x << 16) + __uint_as_float(u3.x << 16);
        acc.y += __uint_as_float(u0.x & 0xFFFF0000u) + __uint_as_float(u1.x & 0xFFFF0000u)
               + __uint_as_float(u2.x & 0xFFFF0000u) + __uint_as_float(u3.x & 0xFFFF0000u);
        acc.z += __uint_as_float(u0.y << 16) + __uint_as_float(u1.y << 16)
               + __uint_as_float(u2.y << 16) + __uint_as_float(u3.y << 16);
        acc.w += __uint_as_float(u0.y & 0xFFFF0000u) + __uint_as_float(u1.y & 0xFFFF0000u)
               + __uint_as_float(u2.y & 0xFFFF0000u) + __uint_as_float(u3.y & 0xFFFF0000u);
    }
    for (; k < c; ++k) {
        int s0 = ep[k];
        uint2 u0 = *(const uint2*)(tab + (size_t)s0 * H_F + co);
        acc.x += __uint_as_float(u0.x << 16);
        acc.y += __uint_as_float(u0.x & 0xFFFF0000u);
        acc.z += __uint_as_float(u0.y << 16);
        acc.w += __uint_as_float(u0.y & 0xFFFF0000u);
    }
    // self term + scale + bias + relu
    uint2 us = *(const uint2*)(tab + (size_t)node * H_F + co);
    acc.x += __uint_as_float(us.x << 16);
    acc.y += __uint_as_float(us.x & 0xFFFF0000u);
    acc.z += __uint_as_float(us.y << 16);
    acc.w += __uint_as_float(us.y & 0xFFFF0000u);
    float s = dinv[node] / (float)(c + 1);
    float4 bv = *(const float4*)(bias + co);
    float4 o;
    o.x = fmaxf(fmaf(acc.x, s, bv.x), 0.f);
    o.y = fmaxf(fmaf(acc.y, s, bv.y), 0.f);
    o.z = fmaxf(fmaf(acc.z, s, bv.z), 0.f);
    o.w = fmaxf(fmaf(acc.w, s, bv.w), 0.f);

    if (!FUSE_OUT) {
        *(float4*)(outp + (size_t)node * H_F + co) = o;
    } else {
        float po[C_OUT];
#pragma unroll
        for (int cc = 0; cc < C_OUT; ++cc) {
            float t = o.x * Wc[(co + 0) * C_OUT + cc];
            t = fmaf(o.y, Wc[(co + 1) * C_OUT + cc], t);
            t = fmaf(o.z, Wc[(co + 2) * C_OUT + cc], t);
            po[cc] = fmaf(o.w, Wc[(co + 3) * C_OUT + cc], t);
        }
#pragma unroll
        for (int off = 16; off; off >>= 1)
#pragma unroll
            for (int cc = 0; cc < C_OUT; ++cc)
                po[cc] += __shfl_xor(po[cc], off, 64);   // offsets <32 stay in-half
        if (sl == 0) {
#pragma unroll
            for (int cc = 0; cc < C_OUT; ++cc)
                outp[(size_t)node * C_OUT + cc] = po[cc] + bc[cc];
        }
    }
}

// ---------------- launch ----------------

extern "C" void kernel_launch(void* const* d_in, const int* in_sizes, int n_in,
                              void* d_out, int out_size, void* d_ws, size_t ws_size,
                              hipStream_t stream) {
    const float* x  = (const float*)d_in[0];
    const int*   ei = (const int*)d_in[1];
    const float* W1 = (const float*)d_in[2];
    const float* b1 = (const float*)d_in[3];
    const float* W2 = (const float*)d_in[4];
    const float* b2 = (const float*)d_in[5];
    const float* Wc = (const float*)d_in[6];
    const float* bc = (const float*)d_in[7];
    const int* esrc = ei;
    const int* edst = ei + E_EDGES;

    char* ws = (char*)d_ws;
    int*   cnt     = (int*)ws;                    ws += sizeof(int) * N_NODES;
    int*   row_off = (int*)ws;                    ws += sizeof(int) * N_NODES;
    int*   cursor  = (int*)ws;                    ws += sizeof(int) * N_NODES;
    float* dinv    = (float*)ws;                  ws += sizeof(float) * N_NODES;
    int*   part    = (int*)ws;                    ws += sizeof(int) * 256;
    ws = (char*)(((size_t)ws + 15) & ~(size_t)15);
    int*   csr_src = (int*)ws;                    ws += sizeof(int) * E_EDGES;
    unsigned short* B1h = (unsigned short*)ws;    ws += sizeof(short) * IN_F * H_F;
    unsigned short* B1l = (unsigned short*)ws;    ws += sizeof(short) * IN_F * H_F;
    unsigned short* B2h = (unsigned short*)ws;    ws += sizeof(short) * H_F * H_F;
    unsigned short* B2l = (unsigned short*)ws;    ws += sizeof(short) * H_F * H_F;
    unsigned short* tabBF = (unsigned short*)ws;  ws += sizeof(short) * (size_t)N_NODES * H_F;
    float* h1      = (float*)ws;                  ws += sizeof(float) * (size_t)N_NODES * H_F;

    const int gE = (E_EDGES + 255) / 256;
    const int gAgg = (N_NODES + 7) / 8;
    const int gGemm = (N_NODES + 127) / 128;
    const int gConv = (IN_F * H_F + H_F * H_F + 255) / 256;

    // CSR build (graph fixed per call; rebuilt every call for determinism)
    hipMemsetAsync(cnt, 0, sizeof(int) * N_NODES, stream);
    k_count<<<gE, 256, 0, stream>>>(edst, cnt);
    k_scan1<<<NB_SCAN, 256, 0, stream>>>(cnt, row_off, part);
    k_scan2<<<1, 256, 0, stream>>>(part);
    k_scan3<<<NB_SCAN, 256, 0, stream>>>(cnt, part, row_off, cursor, dinv);
    k_bucket<<<gE, 256, 0, stream>>>(esrc, edst, cursor, csr_src);
    k_convB<<<gConv, 256, 0, stream>>>(W1, W2, B1h, B1l, B2h, B2l);

    // layer 1 (GEMM emits bf16 gather table, pre-scaled by dinv)
    k_gemm_mfma<IN_F><<<gGemm, 256, 0, stream>>>(x, B1h, B1l, dinv, tabBF);
    k_agg<false><<<gAgg, 256, 0, stream>>>(tabBF, row_off, cnt, csr_src, dinv, b1,
                                           nullptr, nullptr, h1);

    // layer 2 (+ fused classifier)
    k_gemm_mfma<H_F><<<gGemm, 256, 0, stream>>>(h1, B2h, B2l, dinv, tabBF);
    k_agg<true><<<gAgg, 256, 0, stream>>>(tabBF, row_off, cnt, csr_src, dinv, b2,
                                          Wc, bc, (float*)d_out);
}